// Round 6
// baseline (359.255 us; speedup 1.0000x reference)
//
#include <hip/hip_runtime.h>
#include <math.h>

#define NHID 128
#define NFEAT 256
#define NCLASS 40

typedef __bf16 bf16x8 __attribute__((ext_vector_type(8)));
typedef __bf16 bf16x4 __attribute__((ext_vector_type(4)));
typedef float floatx4 __attribute__((ext_vector_type(4)));

// ===========================================================================
// CSR build via 2-level bucketed counting sort. (round-3, verified)
// ===========================================================================
__global__ __launch_bounds__(256) void bucket_hist(const int* __restrict__ edst,
                                                   int* __restrict__ bucket_counts,
                                                   int E, int nbuck) {
    __shared__ int lh[256];
    int tid = threadIdx.x;
    lh[tid] = 0;
    __syncthreads();
    int base = blockIdx.x * 4096;
#pragma unroll
    for (int k = 0; k < 16; ++k) {
        int e = base + k * 256 + tid;
        if (e < E) atomicAdd(&lh[edst[e] >> 8], 1);
    }
    __syncthreads();
    if (tid < nbuck && lh[tid]) atomicAdd(&bucket_counts[tid], lh[tid]);
}

__global__ __launch_bounds__(256) void bucket_scan(const int* __restrict__ counts,
                                                   int* __restrict__ start,
                                                   int* __restrict__ cursor,
                                                   int* __restrict__ row_ptr,
                                                   int nbuck, int E, int N) {
    __shared__ int lds[256];
    int tid = threadIdx.x;
    int v = (tid < nbuck) ? counts[tid] : 0;
    lds[tid] = v;
    __syncthreads();
    for (int off = 1; off < 256; off <<= 1) {
        int t = (tid >= off) ? lds[tid - off] : 0;
        __syncthreads();
        lds[tid] += t;
        __syncthreads();
    }
    int excl = lds[tid] - v;
    if (tid < nbuck) { start[tid] = excl; cursor[tid] = excl; }
    if (tid == 0) { start[nbuck] = E; row_ptr[N] = E; }
}

__global__ __launch_bounds__(256) void bucket_scatter(const int* __restrict__ esrc,
                                                      const int* __restrict__ edst,
                                                      int* __restrict__ cursor,
                                                      unsigned int* __restrict__ bdata,
                                                      int E, int nbuck) {
    __shared__ int lh[256];
    __shared__ int lbase[256];
    int tid = threadIdx.x;
    lh[tid] = 0;
    __syncthreads();
    int base = blockIdx.x * 4096;
    unsigned int recs[16];
    short bks[16];
    short lofs[16];
#pragma unroll
    for (int k = 0; k < 16; ++k) {
        int e = base + k * 256 + tid;
        bks[k] = -1;
        if (e < E) {
            int d = edst[e];
            int s = esrc[e];
            int b = d >> 8;
            recs[k] = ((unsigned int)(d & 255) << 16) | (unsigned int)s;
            bks[k] = (short)b;
            lofs[k] = (short)atomicAdd(&lh[b], 1);
        }
    }
    __syncthreads();
    if (tid < nbuck && lh[tid]) lbase[tid] = atomicAdd(&cursor[tid], lh[tid]);
    __syncthreads();
#pragma unroll
    for (int k = 0; k < 16; ++k) {
        if (bks[k] >= 0) bdata[lbase[bks[k]] + lofs[k]] = recs[k];
    }
}

__global__ __launch_bounds__(256) void bucket_finalize(const unsigned int* __restrict__ bdata,
                                                       const int* __restrict__ start,
                                                       int* __restrict__ row_ptr,
                                                       int* __restrict__ srcs,
                                                       int N) {
    __shared__ int hist[256];
    __shared__ int cur[256];
    int b = blockIdx.x;
    int tid = threadIdx.x;
    int s0 = start[b];
    int cnt = start[b + 1] - s0;
    hist[tid] = 0;
    __syncthreads();
    for (int i = tid; i < cnt; i += 256) atomicAdd(&hist[bdata[s0 + i] >> 16], 1);
    __syncthreads();
    int v0 = hist[tid];
    __syncthreads();
    for (int off = 1; off < 256; off <<= 1) {
        int t = (tid >= off) ? hist[tid - off] : 0;
        __syncthreads();
        hist[tid] += t;
        __syncthreads();
    }
    int excl = hist[tid] - v0;
    cur[tid] = excl;
    int node = b * 256 + tid;
    if (node < N) row_ptr[node] = s0 + excl;
    __syncthreads();
    for (int i = tid; i < cnt; i += 256) {
        unsigned int r = bdata[s0 + i];
        int p = atomicAdd(&cur[r >> 16], 1);
        srcs[s0 + p] = (int)(r & 0xffffu);
    }
}

// ===========================================================================
// Weight prep (single launch): W_in (K=256) then W_mlps (3x, K=128).
// ===========================================================================
__global__ __launch_bounds__(256) void transpose_split_all(
    const float* __restrict__ W_in, const float* __restrict__ W_mlps,
    __bf16* __restrict__ in_hi, __bf16* __restrict__ in_lo,
    __bf16* __restrict__ ml_hi, __bf16* __restrict__ ml_lo) {
    int i = blockIdx.x * 256 + threadIdx.x;
    const int total1 = 128 * NFEAT;
    const int total2 = 3 * 128 * NHID;
    if (i < total1) {
        int n = i >> 8, k = i & 255;
        float v = W_in[(size_t)k * 128 + n];
        __bf16 hi = (__bf16)v;
        in_hi[i] = hi;
        in_lo[i] = (__bf16)(v - (float)hi);
    } else if (i < total1 + total2) {
        int j = i - total1;
        int l = j >> 14;
        int r = j & 16383;
        int n = r >> 7, k = r & 127;
        float v = W_mlps[(size_t)l * 16384 + (size_t)k * 128 + n];
        __bf16 hi = (__bf16)v;
        ml_hi[j] = hi;
        ml_lo[j] = (__bf16)(v - (float)hi);
    }
}

// ===========================================================================
// Feature-quartered aggregation: sum = h[node](hi+lo) + sum_neighbors h_hi,
// output split bf16 hi/lo. Quarter = 32 features = 64B = one cache line/row;
// per-quarter gather working set = 3.2MB -> fits each XCD's 4MB L2.
// Grid: quarter-major (blocks of the same quarter launch together).
// Wave = 4 nodes x 4 edge-slots x 4 chunks(16B). One gather instr = 16 edges.
// Unroll x2 -> 2 gathers + 2 srcs loads in flight. Reduce: shfl xor 4, 8.
// ===========================================================================
__global__ __launch_bounds__(256) void aggregate_q(
    const __bf16* __restrict__ hhi, const __bf16* __restrict__ hlo,
    const int* __restrict__ row_ptr, const int* __restrict__ srcs,
    __bf16* __restrict__ ohi, __bf16* __restrict__ olo, int N, int ntiles) {
    int bq = blockIdx.x / ntiles;          // quarter 0..3
    int tile = blockIdx.x - bq * ntiles;
    int tid = threadIdx.x;
    int wave = tid >> 6;
    int l = tid & 63;
    int sub = l >> 4;          // node within wave
    int slot = (l >> 2) & 3;   // edge slot
    int c = l & 3;             // 16B chunk within quarter
    int node0 = tile * 16 + wave * 4 + sub;
    int node = min(node0, N - 1);
    int qo = bq * 4 + c;       // bf16x8-chunk index within the 16-chunk row
    int beg = row_ptr[node];
    int end = row_ptr[node + 1];
    const bf16x8* hv = (const bf16x8*)hhi;
    const bf16x8* lv = (const bf16x8*)hlo;

    float a[8], b2[8];
#pragma unroll
    for (int j = 0; j < 8; ++j) { a[j] = 0.f; b2[j] = 0.f; }

    int i = beg + slot;
    for (; i + 4 < end; i += 8) {
        int s0 = srcs[i];
        int s1 = srcs[i + 4];
        bf16x8 v0 = hv[(size_t)s0 * 16 + qo];
        bf16x8 v1 = hv[(size_t)s1 * 16 + qo];
#pragma unroll
        for (int j = 0; j < 8; ++j) { a[j] += (float)v0[j]; b2[j] += (float)v1[j]; }
    }
    if (i < end) {
        int s0 = srcs[i];
        bf16x8 v0 = hv[(size_t)s0 * 16 + qo];
#pragma unroll
        for (int j = 0; j < 8; ++j) a[j] += (float)v0[j];
    }
#pragma unroll
    for (int j = 0; j < 8; ++j) a[j] += b2[j];
#pragma unroll
    for (int j = 0; j < 8; ++j) a[j] += __shfl_xor(a[j], 4);
#pragma unroll
    for (int j = 0; j < 8; ++j) a[j] += __shfl_xor(a[j], 8);

    if (slot == 0 && node0 < N) {
        bf16x8 sh = hv[(size_t)node * 16 + qo];
        bf16x8 sl = lv[(size_t)node * 16 + qo];
        bf16x8 whi, wlo;
#pragma unroll
        for (int j = 0; j < 8; ++j) {
            float v = a[j] + (float)sh[j] + (float)sl[j];
            __bf16 h = (__bf16)v;
            whi[j] = h;
            wlo[j] = (__bf16)(v - (float)h);
        }
        ((bf16x8*)ohi)[(size_t)node * 16 + qo] = whi;
        ((bf16x8*)olo)[(size_t)node * 16 + qo] = wlo;
    }
}

// ===========================================================================
// MFMA GEMM (round-3, verified): out = relu(A @ W + b), N=128.
// MODE 0: A = fp32 Af (input layer, K=256). MODE 1: A = bf16 hi/lo (K=128).
// ===========================================================================
template <int MODE>
__global__ __launch_bounds__(256) void gemm_mfma(
    const float* __restrict__ Af, const __bf16* __restrict__ Ahi,
    const __bf16* __restrict__ Alo,
    const __bf16* __restrict__ Wthi, const __bf16* __restrict__ Wtlo,
    const float* __restrict__ bias, __bf16* __restrict__ Ohi,
    __bf16* __restrict__ Olo, int M, int K) {
    __shared__ __align__(16) char smem[49152];
    __bf16* sAhi = (__bf16*)smem;
    __bf16* sAlo = (__bf16*)(smem + 8192);
    __bf16* sWhi = (__bf16*)(smem + 16384);
    __bf16* sWlo = (__bf16*)(smem + 32768);

    int tid = threadIdx.x;
    int row0 = blockIdx.x * 64;
    int wave = tid >> 6;
    int l = tid & 63;
    int m16 = l & 15;
    int q = l >> 4;
    int axor = m16 & 7;
    int arow = wave * 16 + m16;

    floatx4 acc[8];
#pragma unroll
    for (int t = 0; t < 8; ++t) acc[t] = (floatx4){0.f, 0.f, 0.f, 0.f};

    for (int k0 = 0; k0 < K; k0 += 64) {
#pragma unroll
        for (int it = 0; it < 2; ++it) {
            int lin = it * 2048 + tid * 8;
            int row = lin >> 6, k = lin & 63;
            int g = min(row0 + row, M - 1);
            int off = row * 64 + (((k >> 3) ^ (row & 7)) << 3);
            if (MODE == 0) {
                float4 v0 = *(const float4*)&Af[(size_t)g * K + k0 + k];
                float4 v1 = *(const float4*)&Af[(size_t)g * K + k0 + k + 4];
                float s[8] = {v0.x, v0.y, v0.z, v0.w, v1.x, v1.y, v1.z, v1.w};
                bf16x8 shi, slo;
#pragma unroll
                for (int j = 0; j < 8; ++j) {
                    __bf16 h = (__bf16)s[j];
                    shi[j] = h;
                    slo[j] = (__bf16)(s[j] - (float)h);
                }
                *(bf16x8*)(sAhi + off) = shi;
                *(bf16x8*)(sAlo + off) = slo;
            } else {
                *(bf16x8*)(sAhi + off) = *(const bf16x8*)&Ahi[(size_t)g * 128 + k0 + k];
                *(bf16x8*)(sAlo + off) = *(const bf16x8*)&Alo[(size_t)g * 128 + k0 + k];
            }
        }
#pragma unroll
        for (int it = 0; it < 4; ++it) {
            int lin = it * 2048 + tid * 8;
            int n = lin >> 6, kk = lin & 63;
            int off = n * 64 + (((kk >> 3) ^ (n & 7)) << 3);
            *(bf16x8*)(sWhi + off) = *(const bf16x8*)&Wthi[(size_t)n * K + k0 + kk];
            *(bf16x8*)(sWlo + off) = *(const bf16x8*)&Wtlo[(size_t)n * K + k0 + kk];
        }
        __syncthreads();

#pragma unroll
        for (int s = 0; s < 2; ++s) {
            int sw = (((s * 4 + q) ^ axor) << 3);
            bf16x8 ahi = *(bf16x8*)(sAhi + arow * 64 + sw);
            bf16x8 alo = *(bf16x8*)(sAlo + arow * 64 + sw);
#pragma unroll
            for (int t = 0; t < 8; ++t) {
                int n = t * 16 + m16;
                bf16x8 bhi = *(bf16x8*)(sWhi + n * 64 + sw);
                bf16x8 blo = *(bf16x8*)(sWlo + n * 64 + sw);
                acc[t] = __builtin_amdgcn_mfma_f32_16x16x32_bf16(ahi, bhi, acc[t], 0, 0, 0);
                acc[t] = __builtin_amdgcn_mfma_f32_16x16x32_bf16(alo, bhi, acc[t], 0, 0, 0);
                acc[t] = __builtin_amdgcn_mfma_f32_16x16x32_bf16(ahi, blo, acc[t], 0, 0, 0);
            }
        }
        __syncthreads();
    }

    float* eps = (float*)(smem + 16384);
#pragma unroll
    for (int t = 0; t < 8; ++t) {
        int col = t * 16 + m16;
        float bb = bias[col];
#pragma unroll
        for (int i = 0; i < 4; ++i) {
            int row = wave * 16 + q * 4 + i;
            eps[row * 128 + col] = fmaxf(acc[t][i] + bb, 0.f);
        }
    }
    __syncthreads();
#pragma unroll
    for (int it = 0; it < 8; ++it) {
        int lin = it * 1024 + tid * 4;
        int row = lin >> 7, col = lin & 127;
        int g = row0 + row;
        if (g < M) {
            float4 v = *(float4*)(eps + lin);
            bf16x4 hi, lo;
            float vv[4] = {v.x, v.y, v.z, v.w};
#pragma unroll
            for (int j = 0; j < 4; ++j) {
                __bf16 h = (__bf16)vv[j];
                hi[j] = h;
                lo[j] = (__bf16)(vv[j] - (float)h);
            }
            *(bf16x4*)&Ohi[(size_t)g * 128 + col] = hi;
            *(bf16x4*)&Olo[(size_t)g * 128 + col] = lo;
        }
    }
}

// ===========================================================================
// Output: logits = h @ W_out + b_out (K=128, C=40), then row log_softmax.
// ===========================================================================
__global__ __launch_bounds__(256) void out_logsoftmax(const __bf16* __restrict__ hhi,
                                                      const __bf16* __restrict__ hlo,
                                                      const float* __restrict__ Wout,
                                                      const float* __restrict__ bout,
                                                      float* __restrict__ out, int M) {
    __shared__ float sW[128 * NCLASS];
    __shared__ float sb[NCLASS];
    __shared__ float sH[32 * 132];
    int tid = threadIdx.x;
    for (int i = tid; i < 128 * NCLASS; i += 256) sW[i] = Wout[i];
    if (tid < NCLASS) sb[tid] = bout[tid];
    int row0 = blockIdx.x * 32;
#pragma unroll
    for (int it = 0; it < 4; ++it) {
        int i = tid * 4 + it * 1024;
        int r = i >> 7, k = i & 127;
        int rr = min(row0 + r, M - 1);
        uint2 uh = *(const uint2*)&hhi[(size_t)rr * 128 + k];
        uint2 ul = *(const uint2*)&hlo[(size_t)rr * 128 + k];
        sH[r * 132 + k + 0] = __uint_as_float(uh.x << 16) + __uint_as_float(ul.x << 16);
        sH[r * 132 + k + 1] = __uint_as_float(uh.x & 0xffff0000u) + __uint_as_float(ul.x & 0xffff0000u);
        sH[r * 132 + k + 2] = __uint_as_float(uh.y << 16) + __uint_as_float(ul.y << 16);
        sH[r * 132 + k + 3] = __uint_as_float(uh.y & 0xffff0000u) + __uint_as_float(ul.y & 0xffff0000u);
    }
    __syncthreads();

    int r = tid >> 3;
    int cg = tid & 7;
    float z[5];
#pragma unroll
    for (int j = 0; j < 5; ++j) z[j] = sb[cg * 5 + j];
    for (int k = 0; k < 128; ++k) {
        float a = sH[r * 132 + k];
#pragma unroll
        for (int j = 0; j < 5; ++j) z[j] += a * sW[k * NCLASS + cg * 5 + j];
    }
    float m = z[0];
#pragma unroll
    for (int j = 1; j < 5; ++j) m = fmaxf(m, z[j]);
    for (int off = 1; off < 8; off <<= 1) m = fmaxf(m, __shfl_xor(m, off));
    float s = 0.f;
#pragma unroll
    for (int j = 0; j < 5; ++j) s += expf(z[j] - m);
    for (int off = 1; off < 8; off <<= 1) s += __shfl_xor(s, off);
    float lse = m + logf(s);
    int row = row0 + r;
    if (row < M) {
#pragma unroll
        for (int j = 0; j < 5; ++j) out[(size_t)row * NCLASS + cg * 5 + j] = z[j] - lse;
    }
}

// ===========================================================================
extern "C" void kernel_launch(void* const* d_in, const int* in_sizes, int n_in,
                              void* d_out, int out_size, void* d_ws, size_t ws_size,
                              hipStream_t stream) {
    const float* x      = (const float*)d_in[0];
    const int*   esrc   = (const int*)d_in[1];
    const int*   edst   = (const int*)d_in[2];
    const float* W_in   = (const float*)d_in[3];
    const float* b_in   = (const float*)d_in[4];
    const float* W_mlps = (const float*)d_in[5];
    const float* b_mlps = (const float*)d_in[6];
    const float* W_out  = (const float*)d_in[7];
    const float* b_out  = (const float*)d_in[8];
    float* out = (float*)d_out;

    int N = in_sizes[0] / NFEAT;  // 50000
    int E = in_sizes[1];          // 800000
    int nbuck = (N + 255) >> 8;   // 196

    // workspace carve (~81 MB)
    char* ws = (char*)d_ws;
    size_t hb = (((size_t)N * NHID * sizeof(__bf16)) + 255) & ~(size_t)255;  // 12.8MB
    __bf16* h_hi_a = (__bf16*)ws;
    __bf16* h_lo_a = (__bf16*)(ws + hb);
    __bf16* h_hi_b = (__bf16*)(ws + 2 * hb);
    __bf16* h_lo_b = (__bf16*)(ws + 3 * hb);
    __bf16* sum_hi = (__bf16*)(ws + 4 * hb);
    __bf16* sum_lo = (__bf16*)(ws + 5 * hb);
    // bdata aliases sum_hi's slot: consumed by bucket_finalize before any aggregate
    unsigned int* bdata = (unsigned int*)(ws + 4 * hb);
    char* ip = ws + 6 * hb;
    int* row_ptr = (int*)ip;  ip += (((size_t)(N + 1) * 4) + 255) & ~(size_t)255;
    int* srcs    = (int*)ip;  ip += (((size_t)E * 4) + 255) & ~(size_t)255;
    int* bucket_counts = (int*)ip;  ip += 1024;
    int* bucket_start  = (int*)ip;  ip += 1024;
    int* bucket_cursor = (int*)ip;  ip += 1024;
    __bf16* Wt_in_hi   = (__bf16*)ip;  ip += 128 * NFEAT * 2;
    __bf16* Wt_in_lo   = (__bf16*)ip;  ip += 128 * NFEAT * 2;
    __bf16* Wt_mlps_hi = (__bf16*)ip;  ip += 3 * 128 * NHID * 2;
    __bf16* Wt_mlps_lo = (__bf16*)ip;  ip += 3 * 128 * NHID * 2;

    int eb4 = (E + 4095) / 4096;

    // ---- CSR build ----
    (void)hipMemsetAsync(bucket_counts, 0, 1024, stream);
    bucket_hist<<<eb4, 256, 0, stream>>>(edst, bucket_counts, E, nbuck);
    bucket_scan<<<1, 256, 0, stream>>>(bucket_counts, bucket_start, bucket_cursor,
                                       row_ptr, nbuck, E, N);
    bucket_scatter<<<eb4, 256, 0, stream>>>(esrc, edst, bucket_cursor, bdata, E, nbuck);
    bucket_finalize<<<nbuck, 256, 0, stream>>>(bdata, bucket_start, row_ptr, srcs, N);

    // ---- weight prep ----
    transpose_split_all<<<320, 256, 0, stream>>>(W_in, W_mlps, Wt_in_hi, Wt_in_lo,
                                                 Wt_mlps_hi, Wt_mlps_lo);

    // ---- input layer ----
    gemm_mfma<0><<<(N + 63) / 64, 256, 0, stream>>>(
        x, (const __bf16*)nullptr, (const __bf16*)nullptr,
        Wt_in_hi, Wt_in_lo, b_in, h_hi_a, h_lo_a, N, NFEAT);

    // ---- 3 GIN layers: quartered aggregate + MFMA GEMM ----
    __bf16* cur_hi = h_hi_a; __bf16* cur_lo = h_lo_a;
    __bf16* nxt_hi = h_hi_b; __bf16* nxt_lo = h_lo_b;
    int ntiles = (N + 15) / 16;  // 3125
    for (int i = 0; i < 3; ++i) {
        aggregate_q<<<4 * ntiles, 256, 0, stream>>>(cur_hi, cur_lo, row_ptr, srcs,
                                                    sum_hi, sum_lo, N, ntiles);
        gemm_mfma<1><<<(N + 63) / 64, 256, 0, stream>>>(
            (const float*)nullptr, sum_hi, sum_lo,
            Wt_mlps_hi + (size_t)i * 128 * NHID, Wt_mlps_lo + (size_t)i * 128 * NHID,
            b_mlps + (size_t)i * NHID, nxt_hi, nxt_lo, N, NHID);
        __bf16* t;
        t = cur_hi; cur_hi = nxt_hi; nxt_hi = t;
        t = cur_lo; cur_lo = nxt_lo; nxt_lo = t;
    }

    // ---- output layer + log_softmax ----
    out_logsoftmax<<<(N + 31) / 32, 256, 0, stream>>>(cur_hi, cur_lo, W_out, b_out, out, N);
}

// Round 7
// 357.079 us; speedup vs baseline: 1.0061x; 1.0061x over previous
//
#include <hip/hip_runtime.h>
#include <math.h>

#define NHID 128
#define NFEAT 256
#define NCLASS 40

typedef __bf16 bf16x8 __attribute__((ext_vector_type(8)));
typedef __bf16 bf16x4 __attribute__((ext_vector_type(4)));
typedef float floatx4 __attribute__((ext_vector_type(4)));

// ===========================================================================
// CSR build via 2-level bucketed counting sort.
// Bucket = dst >> 8. Record = (dst&255)<<16 | src  (N <= 65536 holds).
// Round-7: per-block private histograms (no memset, no global atomics).
// ===========================================================================
__global__ __launch_bounds__(256) void bucket_hist(const int* __restrict__ edst,
                                                   int* __restrict__ part_hist,
                                                   int E) {
    __shared__ int lh[256];
    int tid = threadIdx.x;
    lh[tid] = 0;
    __syncthreads();
    int base = blockIdx.x * 4096;
#pragma unroll
    for (int k = 0; k < 16; ++k) {
        int e = base + k * 256 + tid;
        if (e < E) atomicAdd(&lh[edst[e] >> 8], 1);
    }
    __syncthreads();
    part_hist[blockIdx.x * 256 + tid] = lh[tid];
}

__global__ __launch_bounds__(256) void bucket_scan(const int* __restrict__ part_hist,
                                                   int nblk,
                                                   int* __restrict__ start,
                                                   int* __restrict__ cursor,
                                                   int* __restrict__ row_ptr,
                                                   int nbuck, int E, int N) {
    __shared__ int lds[256];
    int tid = threadIdx.x;
    int v = 0;
    for (int b = 0; b < nblk; ++b) v += part_hist[b * 256 + tid];
    lds[tid] = v;
    __syncthreads();
    for (int off = 1; off < 256; off <<= 1) {
        int t = (tid >= off) ? lds[tid - off] : 0;
        __syncthreads();
        lds[tid] += t;
        __syncthreads();
    }
    int excl = lds[tid] - v;
    if (tid < nbuck) { start[tid] = excl; cursor[tid] = excl; }
    if (tid == 0) { start[nbuck] = E; row_ptr[N] = E; }
}

// Pass B: scatter packed records into bucket segments (LDS-aggregated claims).
// Blocks >= eb4 instead do the weight transpose+split (fused to save a launch).
__global__ __launch_bounds__(256) void bucket_scatter(const int* __restrict__ esrc,
                                                      const int* __restrict__ edst,
                                                      int* __restrict__ cursor,
                                                      unsigned int* __restrict__ bdata,
                                                      int E, int nbuck, int eb4,
                                                      const float* __restrict__ W_in,
                                                      const float* __restrict__ W_mlps,
                                                      __bf16* __restrict__ in_hi,
                                                      __bf16* __restrict__ in_lo,
                                                      __bf16* __restrict__ ml_hi,
                                                      __bf16* __restrict__ ml_lo) {
    int tid = threadIdx.x;
    if (blockIdx.x >= eb4) {
        // ---- fused weight prep ----
        int i = (blockIdx.x - eb4) * 256 + tid;
        const int total1 = 128 * NFEAT;
        const int total2 = 3 * 128 * NHID;
        if (i < total1) {
            int n = i >> 8, k = i & 255;
            float v = W_in[(size_t)k * 128 + n];
            __bf16 hi = (__bf16)v;
            in_hi[i] = hi;
            in_lo[i] = (__bf16)(v - (float)hi);
        } else if (i < total1 + total2) {
            int j = i - total1;
            int l = j >> 14;
            int r = j & 16383;
            int n = r >> 7, k = r & 127;
            float v = W_mlps[(size_t)l * 16384 + (size_t)k * 128 + n];
            __bf16 hi = (__bf16)v;
            ml_hi[j] = hi;
            ml_lo[j] = (__bf16)(v - (float)hi);
        }
        return;
    }
    __shared__ int lh[256];
    __shared__ int lbase[256];
    lh[tid] = 0;
    __syncthreads();
    int base = blockIdx.x * 4096;
    unsigned int recs[16];
    short bks[16];
    short lofs[16];
#pragma unroll
    for (int k = 0; k < 16; ++k) {
        int e = base + k * 256 + tid;
        bks[k] = -1;
        if (e < E) {
            int d = edst[e];
            int s = esrc[e];
            int b = d >> 8;
            recs[k] = ((unsigned int)(d & 255) << 16) | (unsigned int)s;
            bks[k] = (short)b;
            lofs[k] = (short)atomicAdd(&lh[b], 1);
        }
    }
    __syncthreads();
    if (tid < nbuck && lh[tid]) lbase[tid] = atomicAdd(&cursor[tid], lh[tid]);
    __syncthreads();
#pragma unroll
    for (int k = 0; k < 16; ++k) {
        if (bks[k] >= 0) bdata[lbase[bks[k]] + lofs[k]] = recs[k];
    }
}

__global__ __launch_bounds__(256) void bucket_finalize(const unsigned int* __restrict__ bdata,
                                                       const int* __restrict__ start,
                                                       int* __restrict__ row_ptr,
                                                       int* __restrict__ srcs,
                                                       int N) {
    __shared__ int hist[256];
    __shared__ int cur[256];
    int b = blockIdx.x;
    int tid = threadIdx.x;
    int s0 = start[b];
    int cnt = start[b + 1] - s0;
    hist[tid] = 0;
    __syncthreads();
    for (int i = tid; i < cnt; i += 256) atomicAdd(&hist[bdata[s0 + i] >> 16], 1);
    __syncthreads();
    int v0 = hist[tid];
    __syncthreads();
    for (int off = 1; off < 256; off <<= 1) {
        int t = (tid >= off) ? hist[tid - off] : 0;
        __syncthreads();
        hist[tid] += t;
        __syncthreads();
    }
    int excl = hist[tid] - v0;
    cur[tid] = excl;
    int node = b * 256 + tid;
    if (node < N) row_ptr[node] = s0 + excl;
    __syncthreads();
    for (int i = tid; i < cnt; i += 256) {
        unsigned int r = bdata[s0 + i];
        int p = atomicAdd(&cur[r >> 16], 1);
        srcs[s0 + p] = (int)(r & 0xffffu);
    }
}

// ===========================================================================
// Fused aggregate (round-3 layout, deeper pipeline): one wave per node.
// 64 lanes = 4 edge-slots x 16 chunks (16B); main loop issues 4 gather
// instructions (16 edges / 16 rows) in flight into 4 accumulator sets.
// sum = h[node](hi+lo) + sum_neighbors h_hi, written as bf16 hi/lo.
// ===========================================================================
__global__ __launch_bounds__(256) void aggregate_fused(const __bf16* __restrict__ hhi,
                                                       const __bf16* __restrict__ hlo,
                                                       const int* __restrict__ row_ptr,
                                                       const int* __restrict__ srcs,
                                                       __bf16* __restrict__ ohi,
                                                       __bf16* __restrict__ olo, int N) {
    int tid = threadIdx.x;
    int node = blockIdx.x * 4 + (tid >> 6);
    if (node >= N) return;
    int l = tid & 63;
    int g = l >> 4;   // edge slot 0..3
    int c = l & 15;   // 16B chunk
    int beg = row_ptr[node];
    int end = row_ptr[node + 1];
    const bf16x8* hv = (const bf16x8*)hhi;
    const bf16x8* lv = (const bf16x8*)hlo;

    float a0[8], a1[8], a2[8], a3[8];
#pragma unroll
    for (int j = 0; j < 8; ++j) { a0[j] = 0.f; a1[j] = 0.f; a2[j] = 0.f; a3[j] = 0.f; }

    int i = beg;
    for (; i + 16 <= end; i += 16) {
        int s0 = srcs[i + g];
        int s1 = srcs[i + 4 + g];
        int s2 = srcs[i + 8 + g];
        int s3 = srcs[i + 12 + g];
        bf16x8 v0 = hv[(size_t)s0 * 16 + c];
        bf16x8 v1 = hv[(size_t)s1 * 16 + c];
        bf16x8 v2 = hv[(size_t)s2 * 16 + c];
        bf16x8 v3 = hv[(size_t)s3 * 16 + c];
#pragma unroll
        for (int j = 0; j < 8; ++j) {
            a0[j] += (float)v0[j];
            a1[j] += (float)v1[j];
            a2[j] += (float)v2[j];
            a3[j] += (float)v3[j];
        }
    }
    if (i + 8 <= end) {
        int s0 = srcs[i + g];
        int s1 = srcs[i + 4 + g];
        bf16x8 v0 = hv[(size_t)s0 * 16 + c];
        bf16x8 v1 = hv[(size_t)s1 * 16 + c];
#pragma unroll
        for (int j = 0; j < 8; ++j) {
            a0[j] += (float)v0[j];
            a1[j] += (float)v1[j];
        }
        i += 8;
    }
    for (; i < end; i += 4) {
        if (i + g < end) {
            int s = srcs[i + g];
            bf16x8 v = hv[(size_t)s * 16 + c];
#pragma unroll
            for (int j = 0; j < 8; ++j) a0[j] += (float)v[j];
        }
    }
#pragma unroll
    for (int j = 0; j < 8; ++j) a0[j] += (a1[j] + a2[j]) + a3[j];
#pragma unroll
    for (int j = 0; j < 8; ++j) a0[j] += __shfl_xor(a0[j], 16);
#pragma unroll
    for (int j = 0; j < 8; ++j) a0[j] += __shfl_xor(a0[j], 32);

    if (g == 0) {
        bf16x8 sh = hv[(size_t)node * 16 + c];
        bf16x8 sl = lv[(size_t)node * 16 + c];
        bf16x8 whi, wlo;
#pragma unroll
        for (int j = 0; j < 8; ++j) {
            float v = a0[j] + (float)sh[j] + (float)sl[j];
            __bf16 h = (__bf16)v;
            whi[j] = h;
            wlo[j] = (__bf16)(v - (float)h);
        }
        ((bf16x8*)ohi)[(size_t)node * 16 + c] = whi;
        ((bf16x8*)olo)[(size_t)node * 16 + c] = wlo;
    }
}

// ===========================================================================
// MFMA GEMM (verified): out = relu(A @ W + b), N=128.
// MODE 0: A = fp32 Af (input layer, K=256). MODE 1: A = bf16 hi/lo (K=128).
// ===========================================================================
template <int MODE>
__global__ __launch_bounds__(256) void gemm_mfma(
    const float* __restrict__ Af, const __bf16* __restrict__ Ahi,
    const __bf16* __restrict__ Alo,
    const __bf16* __restrict__ Wthi, const __bf16* __restrict__ Wtlo,
    const float* __restrict__ bias, __bf16* __restrict__ Ohi,
    __bf16* __restrict__ Olo, int M, int K) {
    __shared__ __align__(16) char smem[49152];
    __bf16* sAhi = (__bf16*)smem;
    __bf16* sAlo = (__bf16*)(smem + 8192);
    __bf16* sWhi = (__bf16*)(smem + 16384);
    __bf16* sWlo = (__bf16*)(smem + 32768);

    int tid = threadIdx.x;
    int row0 = blockIdx.x * 64;
    int wave = tid >> 6;
    int l = tid & 63;
    int m16 = l & 15;
    int q = l >> 4;
    int axor = m16 & 7;
    int arow = wave * 16 + m16;

    floatx4 acc[8];
#pragma unroll
    for (int t = 0; t < 8; ++t) acc[t] = (floatx4){0.f, 0.f, 0.f, 0.f};

    for (int k0 = 0; k0 < K; k0 += 64) {
#pragma unroll
        for (int it = 0; it < 2; ++it) {
            int lin = it * 2048 + tid * 8;
            int row = lin >> 6, k = lin & 63;
            int g = min(row0 + row, M - 1);
            int off = row * 64 + (((k >> 3) ^ (row & 7)) << 3);
            if (MODE == 0) {
                float4 v0 = *(const float4*)&Af[(size_t)g * K + k0 + k];
                float4 v1 = *(const float4*)&Af[(size_t)g * K + k0 + k + 4];
                float s[8] = {v0.x, v0.y, v0.z, v0.w, v1.x, v1.y, v1.z, v1.w};
                bf16x8 shi, slo;
#pragma unroll
                for (int j = 0; j < 8; ++j) {
                    __bf16 h = (__bf16)s[j];
                    shi[j] = h;
                    slo[j] = (__bf16)(s[j] - (float)h);
                }
                *(bf16x8*)(sAhi + off) = shi;
                *(bf16x8*)(sAlo + off) = slo;
            } else {
                *(bf16x8*)(sAhi + off) = *(const bf16x8*)&Ahi[(size_t)g * 128 + k0 + k];
                *(bf16x8*)(sAlo + off) = *(const bf16x8*)&Alo[(size_t)g * 128 + k0 + k];
            }
        }
#pragma unroll
        for (int it = 0; it < 4; ++it) {
            int lin = it * 2048 + tid * 8;
            int n = lin >> 6, kk = lin & 63;
            int off = n * 64 + (((kk >> 3) ^ (n & 7)) << 3);
            *(bf16x8*)(sWhi + off) = *(const bf16x8*)&Wthi[(size_t)n * K + k0 + kk];
            *(bf16x8*)(sWlo + off) = *(const bf16x8*)&Wtlo[(size_t)n * K + k0 + kk];
        }
        __syncthreads();

#pragma unroll
        for (int s = 0; s < 2; ++s) {
            int sw = (((s * 4 + q) ^ axor) << 3);
            bf16x8 ahi = *(bf16x8*)(sAhi + arow * 64 + sw);
            bf16x8 alo = *(bf16x8*)(sAlo + arow * 64 + sw);
#pragma unroll
            for (int t = 0; t < 8; ++t) {
                int n = t * 16 + m16;
                bf16x8 bhi = *(bf16x8*)(sWhi + n * 64 + sw);
                bf16x8 blo = *(bf16x8*)(sWlo + n * 64 + sw);
                acc[t] = __builtin_amdgcn_mfma_f32_16x16x32_bf16(ahi, bhi, acc[t], 0, 0, 0);
                acc[t] = __builtin_amdgcn_mfma_f32_16x16x32_bf16(alo, bhi, acc[t], 0, 0, 0);
                acc[t] = __builtin_amdgcn_mfma_f32_16x16x32_bf16(ahi, blo, acc[t], 0, 0, 0);
            }
        }
        __syncthreads();
    }

    float* eps = (float*)(smem + 16384);
#pragma unroll
    for (int t = 0; t < 8; ++t) {
        int col = t * 16 + m16;
        float bb = bias[col];
#pragma unroll
        for (int i = 0; i < 4; ++i) {
            int row = wave * 16 + q * 4 + i;
            eps[row * 128 + col] = fmaxf(acc[t][i] + bb, 0.f);
        }
    }
    __syncthreads();
#pragma unroll
    for (int it = 0; it < 8; ++it) {
        int lin = it * 1024 + tid * 4;
        int row = lin >> 7, col = lin & 127;
        int g = row0 + row;
        if (g < M) {
            float4 v = *(float4*)(eps + lin);
            bf16x4 hi, lo;
            float vv[4] = {v.x, v.y, v.z, v.w};
#pragma unroll
            for (int j = 0; j < 4; ++j) {
                __bf16 h = (__bf16)vv[j];
                hi[j] = h;
                lo[j] = (__bf16)(vv[j] - (float)h);
            }
            *(bf16x4*)&Ohi[(size_t)g * 128 + col] = hi;
            *(bf16x4*)&Olo[(size_t)g * 128 + col] = lo;
        }
    }
}

// ===========================================================================
// Output: logits = h @ W_out + b_out (K=128, C=40), then row log_softmax.
// ===========================================================================
__global__ __launch_bounds__(256) void out_logsoftmax(const __bf16* __restrict__ hhi,
                                                      const __bf16* __restrict__ hlo,
                                                      const float* __restrict__ Wout,
                                                      const float* __restrict__ bout,
                                                      float* __restrict__ out, int M) {
    __shared__ float sW[128 * NCLASS];
    __shared__ float sb[NCLASS];
    __shared__ float sH[32 * 132];
    int tid = threadIdx.x;
    for (int i = tid; i < 128 * NCLASS; i += 256) sW[i] = Wout[i];
    if (tid < NCLASS) sb[tid] = bout[tid];
    int row0 = blockIdx.x * 32;
#pragma unroll
    for (int it = 0; it < 4; ++it) {
        int i = tid * 4 + it * 1024;
        int r = i >> 7, k = i & 127;
        int rr = min(row0 + r, M - 1);
        uint2 uh = *(const uint2*)&hhi[(size_t)rr * 128 + k];
        uint2 ul = *(const uint2*)&hlo[(size_t)rr * 128 + k];
        sH[r * 132 + k + 0] = __uint_as_float(uh.x << 16) + __uint_as_float(ul.x << 16);
        sH[r * 132 + k + 1] = __uint_as_float(uh.x & 0xffff0000u) + __uint_as_float(ul.x & 0xffff0000u);
        sH[r * 132 + k + 2] = __uint_as_float(uh.y << 16) + __uint_as_float(ul.y << 16);
        sH[r * 132 + k + 3] = __uint_as_float(uh.y & 0xffff0000u) + __uint_as_float(ul.y & 0xffff0000u);
    }
    __syncthreads();

    int r = tid >> 3;
    int cg = tid & 7;
    float z[5];
#pragma unroll
    for (int j = 0; j < 5; ++j) z[j] = sb[cg * 5 + j];
    for (int k = 0; k < 128; ++k) {
        float a = sH[r * 132 + k];
#pragma unroll
        for (int j = 0; j < 5; ++j) z[j] += a * sW[k * NCLASS + cg * 5 + j];
    }
    float m = z[0];
#pragma unroll
    for (int j = 1; j < 5; ++j) m = fmaxf(m, z[j]);
    for (int off = 1; off < 8; off <<= 1) m = fmaxf(m, __shfl_xor(m, off));
    float s = 0.f;
#pragma unroll
    for (int j = 0; j < 5; ++j) s += expf(z[j] - m);
    for (int off = 1; off < 8; off <<= 1) s += __shfl_xor(s, off);
    float lse = m + logf(s);
    int row = row0 + r;
    if (row < M) {
#pragma unroll
        for (int j = 0; j < 5; ++j) out[(size_t)row * NCLASS + cg * 5 + j] = z[j] - lse;
    }
}

// ===========================================================================
extern "C" void kernel_launch(void* const* d_in, const int* in_sizes, int n_in,
                              void* d_out, int out_size, void* d_ws, size_t ws_size,
                              hipStream_t stream) {
    const float* x      = (const float*)d_in[0];
    const int*   esrc   = (const int*)d_in[1];
    const int*   edst   = (const int*)d_in[2];
    const float* W_in   = (const float*)d_in[3];
    const float* b_in   = (const float*)d_in[4];
    const float* W_mlps = (const float*)d_in[5];
    const float* b_mlps = (const float*)d_in[6];
    const float* W_out  = (const float*)d_in[7];
    const float* b_out  = (const float*)d_in[8];
    float* out = (float*)d_out;

    int N = in_sizes[0] / NFEAT;  // 50000
    int E = in_sizes[1];          // 800000
    int nbuck = (N + 255) >> 8;   // 196
    int eb4 = (E + 4095) / 4096;  // 196

    // workspace carve (~81 MB)
    char* ws = (char*)d_ws;
    size_t hb = (((size_t)N * NHID * sizeof(__bf16)) + 255) & ~(size_t)255;  // 12.8MB
    __bf16* h_hi_a = (__bf16*)ws;
    __bf16* h_lo_a = (__bf16*)(ws + hb);
    __bf16* h_hi_b = (__bf16*)(ws + 2 * hb);
    __bf16* h_lo_b = (__bf16*)(ws + 3 * hb);
    __bf16* sum_hi = (__bf16*)(ws + 4 * hb);
    __bf16* sum_lo = (__bf16*)(ws + 5 * hb);
    // bdata aliases sum_hi's slot: consumed by bucket_finalize before any aggregate
    unsigned int* bdata = (unsigned int*)(ws + 4 * hb);
    char* ip = ws + 6 * hb;
    int* row_ptr = (int*)ip;  ip += (((size_t)(N + 1) * 4) + 255) & ~(size_t)255;
    int* srcs    = (int*)ip;  ip += (((size_t)E * 4) + 255) & ~(size_t)255;
    int* part_hist     = (int*)ip;  ip += 256 * 256 * 4;  // eb4(196) x 256 used
    int* bucket_start  = (int*)ip;  ip += 1024;
    int* bucket_cursor = (int*)ip;  ip += 1024;
    __bf16* Wt_in_hi   = (__bf16*)ip;  ip += 128 * NFEAT * 2;
    __bf16* Wt_in_lo   = (__bf16*)ip;  ip += 128 * NFEAT * 2;
    __bf16* Wt_mlps_hi = (__bf16*)ip;  ip += 3 * 128 * NHID * 2;
    __bf16* Wt_mlps_lo = (__bf16*)ip;  ip += 3 * 128 * NHID * 2;

    // ---- CSR build (no memset, no global hist atomics) ----
    bucket_hist<<<eb4, 256, 0, stream>>>(edst, part_hist, E);
    bucket_scan<<<1, 256, 0, stream>>>(part_hist, eb4, bucket_start, bucket_cursor,
                                       row_ptr, nbuck, E, N);
    // scatter + fused weight prep (320 extra blocks)
    bucket_scatter<<<eb4 + 320, 256, 0, stream>>>(esrc, edst, bucket_cursor, bdata,
                                                  E, nbuck, eb4, W_in, W_mlps,
                                                  Wt_in_hi, Wt_in_lo,
                                                  Wt_mlps_hi, Wt_mlps_lo);
    bucket_finalize<<<nbuck, 256, 0, stream>>>(bdata, bucket_start, row_ptr, srcs, N);

    // ---- input layer ----
    gemm_mfma<0><<<(N + 63) / 64, 256, 0, stream>>>(
        x, (const __bf16*)nullptr, (const __bf16*)nullptr,
        Wt_in_hi, Wt_in_lo, b_in, h_hi_a, h_lo_a, N, NFEAT);

    // ---- 3 GIN layers: fused aggregate + MFMA GEMM ----
    __bf16* cur_hi = h_hi_a; __bf16* cur_lo = h_lo_a;
    __bf16* nxt_hi = h_hi_b; __bf16* nxt_lo = h_lo_b;
    for (int i = 0; i < 3; ++i) {
        aggregate_fused<<<(N + 3) / 4, 256, 0, stream>>>(cur_hi, cur_lo, row_ptr, srcs,
                                                         sum_hi, sum_lo, N);
        gemm_mfma<1><<<(N + 63) / 64, 256, 0, stream>>>(
            (const float*)nullptr, sum_hi, sum_lo,
            Wt_mlps_hi + (size_t)i * 128 * NHID, Wt_mlps_lo + (size_t)i * 128 * NHID,
            b_mlps + (size_t)i * NHID, nxt_hi, nxt_lo, N, NHID);
        __bf16* t;
        t = cur_hi; cur_hi = nxt_hi; nxt_hi = t;
        t = cur_lo; cur_lo = nxt_lo; nxt_lo = t;
    }

    // ---- output layer + log_softmax ----
    out_logsoftmax<<<(N + 31) / 32, 256, 0, stream>>>(cur_hi, cur_lo, W_out, b_out, out, N);
}

// Round 8
// 350.571 us; speedup vs baseline: 1.0248x; 1.0186x over previous
//
#include <hip/hip_runtime.h>
#include <math.h>

#define NHID 128
#define NFEAT 256
#define NCLASS 40

typedef __bf16 bf16x8 __attribute__((ext_vector_type(8)));
typedef __bf16 bf16x4 __attribute__((ext_vector_type(4)));
typedef float floatx4 __attribute__((ext_vector_type(4)));

// h layout (quarter-major): hq[q][node][32] bf16, q in [0,4).
// bf16x8-chunk index of (q, node, chunk c in [0,4)): (q*N + node)*4 + c.

// ===========================================================================
// CSR build via 2-level bucketed counting sort. (round-3 verified versions)
// ===========================================================================
__global__ __launch_bounds__(256) void bucket_hist(const int* __restrict__ edst,
                                                   int* __restrict__ bucket_counts,
                                                   int E, int nbuck) {
    __shared__ int lh[256];
    int tid = threadIdx.x;
    lh[tid] = 0;
    __syncthreads();
    int base = blockIdx.x * 4096;
#pragma unroll
    for (int k = 0; k < 16; ++k) {
        int e = base + k * 256 + tid;
        if (e < E) atomicAdd(&lh[edst[e] >> 8], 1);
    }
    __syncthreads();
    if (tid < nbuck && lh[tid]) atomicAdd(&bucket_counts[tid], lh[tid]);
}

__global__ __launch_bounds__(256) void bucket_scan(const int* __restrict__ counts,
                                                   int* __restrict__ start,
                                                   int* __restrict__ cursor,
                                                   int* __restrict__ row_ptr,
                                                   int nbuck, int E, int N) {
    __shared__ int lds[256];
    int tid = threadIdx.x;
    int v = (tid < nbuck) ? counts[tid] : 0;
    lds[tid] = v;
    __syncthreads();
    for (int off = 1; off < 256; off <<= 1) {
        int t = (tid >= off) ? lds[tid - off] : 0;
        __syncthreads();
        lds[tid] += t;
        __syncthreads();
    }
    int excl = lds[tid] - v;
    if (tid < nbuck) { start[tid] = excl; cursor[tid] = excl; }
    if (tid == 0) { start[nbuck] = E; row_ptr[N] = E; }
}

// Pass B: scatter packed records; blocks >= eb4 do weight transpose+split.
__global__ __launch_bounds__(256) void bucket_scatter(const int* __restrict__ esrc,
                                                      const int* __restrict__ edst,
                                                      int* __restrict__ cursor,
                                                      unsigned int* __restrict__ bdata,
                                                      int E, int nbuck, int eb4,
                                                      const float* __restrict__ W_in,
                                                      const float* __restrict__ W_mlps,
                                                      __bf16* __restrict__ in_hi,
                                                      __bf16* __restrict__ in_lo,
                                                      __bf16* __restrict__ ml_hi,
                                                      __bf16* __restrict__ ml_lo) {
    int tid = threadIdx.x;
    if (blockIdx.x >= eb4) {
        int i = (blockIdx.x - eb4) * 256 + tid;
        const int total1 = 128 * NFEAT;
        const int total2 = 3 * 128 * NHID;
        if (i < total1) {
            int n = i >> 8, k = i & 255;
            float v = W_in[(size_t)k * 128 + n];
            __bf16 hi = (__bf16)v;
            in_hi[i] = hi;
            in_lo[i] = (__bf16)(v - (float)hi);
        } else if (i < total1 + total2) {
            int j = i - total1;
            int l = j >> 14;
            int r = j & 16383;
            int n = r >> 7, k = r & 127;
            float v = W_mlps[(size_t)l * 16384 + (size_t)k * 128 + n];
            __bf16 hi = (__bf16)v;
            ml_hi[j] = hi;
            ml_lo[j] = (__bf16)(v - (float)hi);
        }
        return;
    }
    __shared__ int lh[256];
    __shared__ int lbase[256];
    lh[tid] = 0;
    __syncthreads();
    int base = blockIdx.x * 4096;
    unsigned int recs[16];
    short bks[16];
    short lofs[16];
#pragma unroll
    for (int k = 0; k < 16; ++k) {
        int e = base + k * 256 + tid;
        bks[k] = -1;
        if (e < E) {
            int d = edst[e];
            int s = esrc[e];
            int b = d >> 8;
            recs[k] = ((unsigned int)(d & 255) << 16) | (unsigned int)s;
            bks[k] = (short)b;
            lofs[k] = (short)atomicAdd(&lh[b], 1);
        }
    }
    __syncthreads();
    if (tid < nbuck && lh[tid]) lbase[tid] = atomicAdd(&cursor[tid], lh[tid]);
    __syncthreads();
#pragma unroll
    for (int k = 0; k < 16; ++k) {
        if (bks[k] >= 0) bdata[lbase[bks[k]] + lofs[k]] = recs[k];
    }
}

__global__ __launch_bounds__(256) void bucket_finalize(const unsigned int* __restrict__ bdata,
                                                       const int* __restrict__ start,
                                                       int* __restrict__ row_ptr,
                                                       int* __restrict__ srcs,
                                                       int N) {
    __shared__ int hist[256];
    __shared__ int cur[256];
    int b = blockIdx.x;
    int tid = threadIdx.x;
    int s0 = start[b];
    int cnt = start[b + 1] - s0;
    hist[tid] = 0;
    __syncthreads();
    for (int i = tid; i < cnt; i += 256) atomicAdd(&hist[bdata[s0 + i] >> 16], 1);
    __syncthreads();
    int v0 = hist[tid];
    __syncthreads();
    for (int off = 1; off < 256; off <<= 1) {
        int t = (tid >= off) ? hist[tid - off] : 0;
        __syncthreads();
        hist[tid] += t;
        __syncthreads();
    }
    int excl = hist[tid] - v0;
    cur[tid] = excl;
    int node = b * 256 + tid;
    if (node < N) row_ptr[node] = s0 + excl;
    __syncthreads();
    for (int i = tid; i < cnt; i += 256) {
        unsigned int r = bdata[s0 + i];
        int p = atomicAdd(&cur[r >> 16], 1);
        srcs[s0 + p] = (int)(r & 0xffffu);
    }
}

// ===========================================================================
// Quarter-major aggregation (round-6 kernel + PHYSICAL quarter-major layout):
// per quarter the gather working set is a contiguous 3.2MB array -> resident
// in each XCD's 4MB L2 during its quarter-epoch (grid is quarter-major).
// Wave = 4 nodes x 4 edge-slots x 4 chunks(16B). 2 gathers + 2 srcs in flight.
// sum = h[node](hi+lo) + sum_neighbors h_hi, written bf16 hi/lo quarter-major.
// ===========================================================================
__global__ __launch_bounds__(256) void aggregate_q(
    const __bf16* __restrict__ hhi, const __bf16* __restrict__ hlo,
    const int* __restrict__ row_ptr, const int* __restrict__ srcs,
    __bf16* __restrict__ ohi, __bf16* __restrict__ olo, int N, int ntiles) {
    int bq = blockIdx.x / ntiles;          // quarter 0..3
    int tile = blockIdx.x - bq * ntiles;
    int tid = threadIdx.x;
    int wave = tid >> 6;
    int l = tid & 63;
    int sub = l >> 4;          // node within wave
    int slot = (l >> 2) & 3;   // edge slot
    int c = l & 3;             // 16B chunk within quarter
    int node0 = tile * 16 + wave * 4 + sub;
    int node = min(node0, N - 1);
    size_t qbase = (size_t)bq * N;         // quarter-array base (in rows)
    int beg = row_ptr[node];
    int end = row_ptr[node + 1];
    const bf16x8* hv = (const bf16x8*)hhi;
    const bf16x8* lv = (const bf16x8*)hlo;

    float a[8], b2[8];
#pragma unroll
    for (int j = 0; j < 8; ++j) { a[j] = 0.f; b2[j] = 0.f; }

    int i = beg + slot;
    for (; i + 4 < end; i += 8) {
        int s0 = srcs[i];
        int s1 = srcs[i + 4];
        bf16x8 v0 = hv[(qbase + s0) * 4 + c];
        bf16x8 v1 = hv[(qbase + s1) * 4 + c];
#pragma unroll
        for (int j = 0; j < 8; ++j) { a[j] += (float)v0[j]; b2[j] += (float)v1[j]; }
    }
    if (i < end) {
        int s0 = srcs[i];
        bf16x8 v0 = hv[(qbase + s0) * 4 + c];
#pragma unroll
        for (int j = 0; j < 8; ++j) a[j] += (float)v0[j];
    }
#pragma unroll
    for (int j = 0; j < 8; ++j) a[j] += b2[j];
#pragma unroll
    for (int j = 0; j < 8; ++j) a[j] += __shfl_xor(a[j], 4);
#pragma unroll
    for (int j = 0; j < 8; ++j) a[j] += __shfl_xor(a[j], 8);

    if (slot == 0 && node0 < N) {
        size_t idx = (qbase + node) * 4 + c;
        bf16x8 sh = hv[idx];
        bf16x8 sl = lv[idx];
        bf16x8 whi, wlo;
#pragma unroll
        for (int j = 0; j < 8; ++j) {
            float v = a[j] + (float)sh[j] + (float)sl[j];
            __bf16 h = (__bf16)v;
            whi[j] = h;
            wlo[j] = (__bf16)(v - (float)h);
        }
        ((bf16x8*)ohi)[idx] = whi;
        ((bf16x8*)olo)[idx] = wlo;
    }
}

// ===========================================================================
// MFMA GEMM: out = relu(A @ W + b), N=128 output cols, quarter-major output.
// MODE 0: A = fp32 Af row-major (input layer, K=256).
// MODE 1: A = bf16 hi/lo quarter-major (K=128).
// ===========================================================================
template <int MODE>
__global__ __launch_bounds__(256) void gemm_mfma(
    const float* __restrict__ Af, const __bf16* __restrict__ Ahi,
    const __bf16* __restrict__ Alo,
    const __bf16* __restrict__ Wthi, const __bf16* __restrict__ Wtlo,
    const float* __restrict__ bias, __bf16* __restrict__ Ohi,
    __bf16* __restrict__ Olo, int M, int K) {
    __shared__ __align__(16) char smem[49152];
    __bf16* sAhi = (__bf16*)smem;
    __bf16* sAlo = (__bf16*)(smem + 8192);
    __bf16* sWhi = (__bf16*)(smem + 16384);
    __bf16* sWlo = (__bf16*)(smem + 32768);

    int tid = threadIdx.x;
    int row0 = blockIdx.x * 64;
    int wave = tid >> 6;
    int l = tid & 63;
    int m16 = l & 15;
    int q = l >> 4;
    int axor = m16 & 7;
    int arow = wave * 16 + m16;

    floatx4 acc[8];
#pragma unroll
    for (int t = 0; t < 8; ++t) acc[t] = (floatx4){0.f, 0.f, 0.f, 0.f};

    for (int k0 = 0; k0 < K; k0 += 64) {
#pragma unroll
        for (int it = 0; it < 2; ++it) {
            int lin = it * 2048 + tid * 8;
            int row = lin >> 6, k = lin & 63;
            int g = min(row0 + row, M - 1);
            int off = row * 64 + (((k >> 3) ^ (row & 7)) << 3);
            if (MODE == 0) {
                float4 v0 = *(const float4*)&Af[(size_t)g * K + k0 + k];
                float4 v1 = *(const float4*)&Af[(size_t)g * K + k0 + k + 4];
                float s[8] = {v0.x, v0.y, v0.z, v0.w, v1.x, v1.y, v1.z, v1.w};
                bf16x8 shi, slo;
#pragma unroll
                for (int j = 0; j < 8; ++j) {
                    __bf16 h = (__bf16)s[j];
                    shi[j] = h;
                    slo[j] = (__bf16)(s[j] - (float)h);
                }
                *(bf16x8*)(sAhi + off) = shi;
                *(bf16x8*)(sAlo + off) = slo;
            } else {
                // quarter-major A: feature f = k0+k; chunk = (f>>3)&3; quarter = f>>5
                int f = k0 + k;
                size_t idx = ((size_t)(f >> 5) * M + g) * 4 + ((f >> 3) & 3);
                *(bf16x8*)(sAhi + off) = ((const bf16x8*)Ahi)[idx];
                *(bf16x8*)(sAlo + off) = ((const bf16x8*)Alo)[idx];
            }
        }
#pragma unroll
        for (int it = 0; it < 4; ++it) {
            int lin = it * 2048 + tid * 8;
            int n = lin >> 6, kk = lin & 63;
            int off = n * 64 + (((kk >> 3) ^ (n & 7)) << 3);
            *(bf16x8*)(sWhi + off) = *(const bf16x8*)&Wthi[(size_t)n * K + k0 + kk];
            *(bf16x8*)(sWlo + off) = *(const bf16x8*)&Wtlo[(size_t)n * K + k0 + kk];
        }
        __syncthreads();

#pragma unroll
        for (int s = 0; s < 2; ++s) {
            int sw = (((s * 4 + q) ^ axor) << 3);
            bf16x8 ahi = *(bf16x8*)(sAhi + arow * 64 + sw);
            bf16x8 alo = *(bf16x8*)(sAlo + arow * 64 + sw);
#pragma unroll
            for (int t = 0; t < 8; ++t) {
                int n = t * 16 + m16;
                bf16x8 bhi = *(bf16x8*)(sWhi + n * 64 + sw);
                bf16x8 blo = *(bf16x8*)(sWlo + n * 64 + sw);
                acc[t] = __builtin_amdgcn_mfma_f32_16x16x32_bf16(ahi, bhi, acc[t], 0, 0, 0);
                acc[t] = __builtin_amdgcn_mfma_f32_16x16x32_bf16(alo, bhi, acc[t], 0, 0, 0);
                acc[t] = __builtin_amdgcn_mfma_f32_16x16x32_bf16(ahi, blo, acc[t], 0, 0, 0);
            }
        }
        __syncthreads();
    }

    float* eps = (float*)(smem + 16384);
#pragma unroll
    for (int t = 0; t < 8; ++t) {
        int col = t * 16 + m16;
        float bb = bias[col];
#pragma unroll
        for (int i = 0; i < 4; ++i) {
            int row = wave * 16 + q * 4 + i;
            eps[row * 128 + col] = fmaxf(acc[t][i] + bb, 0.f);
        }
    }
    __syncthreads();
#pragma unroll
    for (int it = 0; it < 8; ++it) {
        int lin = it * 1024 + tid * 4;
        int row = lin >> 7, col = lin & 127;
        int g = row0 + row;
        if (g < M) {
            float4 v = *(float4*)(eps + lin);
            bf16x4 hi, lo;
            float vv[4] = {v.x, v.y, v.z, v.w};
#pragma unroll
            for (int j = 0; j < 4; ++j) {
                __bf16 h = (__bf16)vv[j];
                hi[j] = h;
                lo[j] = (__bf16)(vv[j] - (float)h);
            }
            // quarter-major store
            size_t bidx = ((size_t)(col >> 5) * M + g) * 32 + (col & 31);
            *(bf16x4*)&Ohi[bidx] = hi;
            *(bf16x4*)&Olo[bidx] = lo;
        }
    }
}

// ===========================================================================
// Output: logits = h @ W_out + b_out (K=128, C=40), then row log_softmax.
// h read from quarter-major hi/lo.
// ===========================================================================
__global__ __launch_bounds__(256) void out_logsoftmax(const __bf16* __restrict__ hhi,
                                                      const __bf16* __restrict__ hlo,
                                                      const float* __restrict__ Wout,
                                                      const float* __restrict__ bout,
                                                      float* __restrict__ out, int M) {
    __shared__ float sW[128 * NCLASS];
    __shared__ float sb[NCLASS];
    __shared__ float sH[32 * 132];
    int tid = threadIdx.x;
    for (int i = tid; i < 128 * NCLASS; i += 256) sW[i] = Wout[i];
    if (tid < NCLASS) sb[tid] = bout[tid];
    int row0 = blockIdx.x * 32;
#pragma unroll
    for (int it = 0; it < 4; ++it) {
        int i = tid * 4 + it * 1024;
        int r = i >> 7, k = i & 127;
        int rr = min(row0 + r, M - 1);
        size_t bidx = ((size_t)(k >> 5) * M + rr) * 32 + (k & 31);
        uint2 uh = *(const uint2*)&hhi[bidx];
        uint2 ul = *(const uint2*)&hlo[bidx];
        sH[r * 132 + k + 0] = __uint_as_float(uh.x << 16) + __uint_as_float(ul.x << 16);
        sH[r * 132 + k + 1] = __uint_as_float(uh.x & 0xffff0000u) + __uint_as_float(ul.x & 0xffff0000u);
        sH[r * 132 + k + 2] = __uint_as_float(uh.y << 16) + __uint_as_float(ul.y << 16);
        sH[r * 132 + k + 3] = __uint_as_float(uh.y & 0xffff0000u) + __uint_as_float(ul.y & 0xffff0000u);
    }
    __syncthreads();

    int r = tid >> 3;
    int cg = tid & 7;
    float z[5];
#pragma unroll
    for (int j = 0; j < 5; ++j) z[j] = sb[cg * 5 + j];
    for (int k = 0; k < 128; ++k) {
        float a = sH[r * 132 + k];
#pragma unroll
        for (int j = 0; j < 5; ++j) z[j] += a * sW[k * NCLASS + cg * 5 + j];
    }
    float m = z[0];
#pragma unroll
    for (int j = 1; j < 5; ++j) m = fmaxf(m, z[j]);
    for (int off = 1; off < 8; off <<= 1) m = fmaxf(m, __shfl_xor(m, off));
    float s = 0.f;
#pragma unroll
    for (int j = 0; j < 5; ++j) s += expf(z[j] - m);
    for (int off = 1; off < 8; off <<= 1) s += __shfl_xor(s, off);
    float lse = m + logf(s);
    int row = row0 + r;
    if (row < M) {
#pragma unroll
        for (int j = 0; j < 5; ++j) out[(size_t)row * NCLASS + cg * 5 + j] = z[j] - lse;
    }
}

// ===========================================================================
extern "C" void kernel_launch(void* const* d_in, const int* in_sizes, int n_in,
                              void* d_out, int out_size, void* d_ws, size_t ws_size,
                              hipStream_t stream) {
    const float* x      = (const float*)d_in[0];
    const int*   esrc   = (const int*)d_in[1];
    const int*   edst   = (const int*)d_in[2];
    const float* W_in   = (const float*)d_in[3];
    const float* b_in   = (const float*)d_in[4];
    const float* W_mlps = (const float*)d_in[5];
    const float* b_mlps = (const float*)d_in[6];
    const float* W_out  = (const float*)d_in[7];
    const float* b_out  = (const float*)d_in[8];
    float* out = (float*)d_out;

    int N = in_sizes[0] / NFEAT;  // 50000
    int E = in_sizes[1];          // 800000
    int nbuck = (N + 255) >> 8;   // 196
    int eb4 = (E + 4095) / 4096;  // 196

    // workspace carve (~81 MB)
    char* ws = (char*)d_ws;
    size_t hb = (((size_t)N * NHID * sizeof(__bf16)) + 255) & ~(size_t)255;  // 12.8MB
    __bf16* h_hi_a = (__bf16*)ws;
    __bf16* h_lo_a = (__bf16*)(ws + hb);
    __bf16* h_hi_b = (__bf16*)(ws + 2 * hb);
    __bf16* h_lo_b = (__bf16*)(ws + 3 * hb);
    __bf16* sum_hi = (__bf16*)(ws + 4 * hb);
    __bf16* sum_lo = (__bf16*)(ws + 5 * hb);
    // bdata aliases sum_hi's slot: consumed by bucket_finalize before any aggregate
    unsigned int* bdata = (unsigned int*)(ws + 4 * hb);
    char* ip = ws + 6 * hb;
    int* row_ptr = (int*)ip;  ip += (((size_t)(N + 1) * 4) + 255) & ~(size_t)255;
    int* srcs    = (int*)ip;  ip += (((size_t)E * 4) + 255) & ~(size_t)255;
    int* bucket_counts = (int*)ip;  ip += 1024;
    int* bucket_start  = (int*)ip;  ip += 1024;
    int* bucket_cursor = (int*)ip;  ip += 1024;
    __bf16* Wt_in_hi   = (__bf16*)ip;  ip += 128 * NFEAT * 2;
    __bf16* Wt_in_lo   = (__bf16*)ip;  ip += 128 * NFEAT * 2;
    __bf16* Wt_mlps_hi = (__bf16*)ip;  ip += 3 * 128 * NHID * 2;
    __bf16* Wt_mlps_lo = (__bf16*)ip;  ip += 3 * 128 * NHID * 2;

    // ---- CSR build (round-3 proven path) + fused weight prep ----
    (void)hipMemsetAsync(bucket_counts, 0, 1024, stream);
    bucket_hist<<<eb4, 256, 0, stream>>>(edst, bucket_counts, E, nbuck);
    bucket_scan<<<1, 256, 0, stream>>>(bucket_counts, bucket_start, bucket_cursor,
                                       row_ptr, nbuck, E, N);
    bucket_scatter<<<eb4 + 320, 256, 0, stream>>>(esrc, edst, bucket_cursor, bdata,
                                                  E, nbuck, eb4, W_in, W_mlps,
                                                  Wt_in_hi, Wt_in_lo,
                                                  Wt_mlps_hi, Wt_mlps_lo);
    bucket_finalize<<<nbuck, 256, 0, stream>>>(bdata, bucket_start, row_ptr, srcs, N);

    // ---- input layer ----
    gemm_mfma<0><<<(N + 63) / 64, 256, 0, stream>>>(
        x, (const __bf16*)nullptr, (const __bf16*)nullptr,
        Wt_in_hi, Wt_in_lo, b_in, h_hi_a, h_lo_a, N, NFEAT);

    // ---- 3 GIN layers: quarter-major aggregate + MFMA GEMM ----
    __bf16* cur_hi = h_hi_a; __bf16* cur_lo = h_lo_a;
    __bf16* nxt_hi = h_hi_b; __bf16* nxt_lo = h_lo_b;
    int ntiles = (N + 15) / 16;  // 3125
    for (int i = 0; i < 3; ++i) {
        aggregate_q<<<4 * ntiles, 256, 0, stream>>>(cur_hi, cur_lo, row_ptr, srcs,
                                                    sum_hi, sum_lo, N, ntiles);
        gemm_mfma<1><<<(N + 63) / 64, 256, 0, stream>>>(
            (const float*)nullptr, sum_hi, sum_lo,
            Wt_mlps_hi + (size_t)i * 128 * NHID, Wt_mlps_lo + (size_t)i * 128 * NHID,
            b_mlps + (size_t)i * NHID, nxt_hi, nxt_lo, N, NHID);
        __bf16* t;
        t = cur_hi; cur_hi = nxt_hi; nxt_hi = t;
        t = cur_lo; cur_lo = nxt_lo; nxt_lo = t;
    }

    // ---- output layer + log_softmax ----
    out_logsoftmax<<<(N + 31) / 32, 256, 0, stream>>>(cur_hi, cur_lo, W_out, b_out, out, N);
}